// Round 5
// baseline (178.751 us; speedup 1.0000x reference)
//
#include <hip/hip_runtime.h>

// Problem constants (fixed by setup_inputs): bs=8, m=4096, T=32, E=65536
#define M      4096
#define TT     32
#define BS     8
#define EE     65536
#define WPR    128                        // 32-bit words per adjacency row (M/32)
#define WPB    (M * WPR)                  // words per batch bit-matrix (2 MB)
#define NROWS  (BS * M)                   // 32768
#define LIST_CAP 64                       // >> max row degree (Poisson mean 16)

// ws layout: [counts 128 KB][bitmap 16 MB][lists 4 MB]
#define CNT_BYTES  ((size_t)NROWS * 4)
#define BITS_BYTES ((size_t)BS * WPB * 4)
#define LIST_BYTES ((size_t)NROWS * LIST_CAP * 2)
#define WS_NEED    (CNT_BYTES + BITS_BYTES + LIST_BYTES)

// ---------------- Fast path: bitmap-dedup build -> compact lists ----------------

__device__ __forceinline__ void add_edge(int src, int tgt, unsigned int* bb,
                                         int* cnt, unsigned short* lists, int rowbase) {
    src &= (M - 1); tgt &= (M - 1);
    unsigned int bit = 1u << (tgt & 31);
    unsigned int old = atomicOr(&bb[src * WPR + (tgt >> 5)], bit);
    if (!(old & bit)) {                           // newly-set -> append (exact dedup)
        int row = rowbase + src;
        int p = atomicAdd(&cnt[row], 1);
        if (p < LIST_CAP) lists[(size_t)row * LIST_CAP + p] = (unsigned short)tgt;
    }
}

__global__ __launch_bounds__(256) void build_lists(const int* __restrict__ coo,
                                                   int* __restrict__ cnt,
                                                   unsigned int* __restrict__ bits,
                                                   unsigned short* __restrict__ lists) {
    int idx = blockIdx.x * 256 + threadIdx.x;     // [0, BS*EE/4)
    int b = idx >> 14;
    int e4 = idx & 16383;
    const int* base = coo + (size_t)b * 2 * EE;
    int4 s = ((const int4*)base)[e4];
    int4 g = ((const int4*)(base + EE))[e4];
    unsigned int* bb = bits + (size_t)b * WPB;
    int rowbase = b * M;
    add_edge(s.x, g.x, bb, cnt, lists, rowbase);
    add_edge(s.y, g.y, bb, cnt, lists, rowbase);
    add_edge(s.z, g.z, bb, cnt, lists, rowbase);
    add_edge(s.w, g.w, bb, cnt, lists, rowbase);
}

// One 32-lane group per row (lane = t). Branch-free countable gather loop.
__global__ __launch_bounds__(256) void compute_lists(const float* __restrict__ y,
                                                     const int* __restrict__ cnt,
                                                     const unsigned short* __restrict__ lists,
                                                     float* __restrict__ out) {
    const int tid = threadIdx.x;
    const int t = tid & 31;
    const int grp = tid >> 5;                      // 8 groups/block
    const int row = blockIdx.x * 8 + grp;          // [0, NROWS)
    const int b = row >> 12;
    const int i = row & (M - 1);

    const float* yb = y + (size_t)b * M * TT;
    int c = cnt[row]; if (c > LIST_CAP) c = LIST_CAP;
    const unsigned short* lp = lists + (size_t)row * LIST_CAP;

    float acc = yb[i * TT + t];                    // identity (eye) term
    float ynext = (t < 31) ? yb[i * TT + t + 1] : 0.0f;

    for (int k0 = 0; k0 < c; k0 += 8) {
        uint4 lv = *(const uint4*)(lp + k0);       // 8 ushort entries, broadcast in group
        int j[8] = { (int)(lv.x & 0xFFFF), (int)(lv.x >> 16),
                     (int)(lv.y & 0xFFFF), (int)(lv.y >> 16),
                     (int)(lv.z & 0xFFFF), (int)(lv.z >> 16),
                     (int)(lv.w & 0xFFFF), (int)(lv.w >> 16) };
        #pragma unroll
        for (int u = 0; u < 8; ++u) {
            float v = yb[(j[u] & (M - 1)) * TT + t];   // mask keeps garbage in-bounds
            acc += (k0 + u < c) ? v : 0.0f;            // tail masked, loads stay independent
        }
    }

    float v = (t < 31) ? fmaxf(ynext - acc, 0.0f) : 0.0f;
    #pragma unroll
    for (int off = 32; off; off >>= 1) v += __shfl_down(v, off, 64);

    __shared__ float wsum[4];
    if ((tid & 63) == 0) wsum[tid >> 6] = v;
    __syncthreads();
    if (tid == 0) atomicAdd(out, wsum[0] + wsum[1] + wsum[2] + wsum[3]);
}

// ---------------- Mid fallback (R4): bitmap only, scan at compute ----------------

__global__ __launch_bounds__(256) void build_adj(const int* __restrict__ coo,
                                                 unsigned int* __restrict__ bits) {
    int idx = blockIdx.x * 256 + threadIdx.x;
    int b = idx >> 14;
    int e4 = idx & 16383;
    const int* base = coo + (size_t)b * 2 * EE;
    int4 s = ((const int4*)base)[e4];
    int4 g = ((const int4*)(base + EE))[e4];
    unsigned int* bb = bits + (size_t)b * WPB;
    atomicOr(&bb[(s.x & (M - 1)) * WPR + ((g.x & (M - 1)) >> 5)], 1u << (g.x & 31));
    atomicOr(&bb[(s.y & (M - 1)) * WPR + ((g.y & (M - 1)) >> 5)], 1u << (g.y & 31));
    atomicOr(&bb[(s.z & (M - 1)) * WPR + ((g.z & (M - 1)) >> 5)], 1u << (g.z & 31));
    atomicOr(&bb[(s.w & (M - 1)) * WPR + ((g.w & (M - 1)) >> 5)], 1u << (g.w & 31));
}

__global__ __launch_bounds__(256) void compute_reg(const float* __restrict__ y,
                                                   const unsigned int* __restrict__ bits,
                                                   float* __restrict__ out) {
    const int tid = threadIdx.x;
    const int t = tid & 31;
    const int grp = tid >> 5;
    const int row = blockIdx.x * 8 + grp;
    const int b = row >> 12;
    const int i = row & (M - 1);
    const float* yb = y + (size_t)b * M * TT;
    const uint4* rw = (const uint4*)(bits + (size_t)b * WPB + (size_t)i * WPR);
    float acc = yb[i * TT + t];
    float ynext = (t < 31) ? yb[i * TT + t + 1] : 0.0f;
    uint4 cur = rw[0];
    #pragma unroll 1
    for (int q = 0; q < 32; ++q) {
        uint4 nxt;
        if (q < 31) nxt = rw[q + 1];
        else { nxt.x = nxt.y = nxt.z = nxt.w = 0u; }
        int jb = q << 7;
        unsigned int w;
        w = cur.x; while (w) { int j = __ffs(w) - 1; w &= w - 1; acc += yb[(jb +      j) * TT + t]; }
        w = cur.y; while (w) { int j = __ffs(w) - 1; w &= w - 1; acc += yb[(jb + 32 + j) * TT + t]; }
        w = cur.z; while (w) { int j = __ffs(w) - 1; w &= w - 1; acc += yb[(jb + 64 + j) * TT + t]; }
        w = cur.w; while (w) { int j = __ffs(w) - 1; w &= w - 1; acc += yb[(jb + 96 + j) * TT + t]; }
        cur = nxt;
    }
    float v = (t < 31) ? fmaxf(ynext - acc, 0.0f) : 0.0f;
    #pragma unroll
    for (int off = 32; off; off >>= 1) v += __shfl_down(v, off, 64);
    __shared__ float wsum[4];
    if ((tid & 63) == 0) wsum[tid >> 6] = v;
    __syncthreads();
    if (tid == 0) atomicAdd(out, wsum[0] + wsum[1] + wsum[2] + wsum[3]);
}

// ---------------- Last-resort fallback (R3): LDS bitmap, no scratch ----------------
#define ROWS   64
#define NCHUNK (M / ROWS)

__global__ __launch_bounds__(256) void nil_reg_lds(const float* __restrict__ y,
                                                   const int* __restrict__ coo,
                                                   float* __restrict__ out) {
    __shared__ unsigned int bm[ROWS * WPR];
    const int tid = threadIdx.x;
    const int b = blockIdx.x / NCHUNK;
    const int chunk = blockIdx.x % NCHUNK;
    const int row0 = chunk * ROWS;
    for (int i = tid; i < ROWS * WPR; i += 256) bm[i] = 0;
    __syncthreads();
    const int* base = coo + (size_t)b * 2 * EE;
    for (int e = tid; e < EE; e += 256) {
        int src = base[e] & (M - 1);
        int tgt = base[EE + e] & (M - 1);
        int r = src - row0;
        if ((unsigned)r < (unsigned)ROWS)
            atomicOr(&bm[r * WPR + (tgt >> 5)], 1u << (tgt & 31));
    }
    __syncthreads();
    const float* yb = y + (size_t)b * M * TT;
    const int t = tid & 31;
    const int grp = tid >> 5;
    float total = 0.0f;
    for (int r = grp; r < ROWS; r += 8) {
        int i = row0 + r;
        float acc = yb[i * TT + t];
        float ynext = (t < 31) ? yb[i * TT + t + 1] : 0.0f;
        const uint4* rwp = (const uint4*)&bm[r * WPR];
        for (int w4 = 0; w4 < WPR / 4; ++w4) {
            uint4 bw = rwp[w4];
            int jb = w4 * 128;
            unsigned int w;
            w = bw.x; while (w) { int j = __ffs(w) - 1; w &= w - 1; acc += yb[(jb +      j) * TT + t]; }
            w = bw.y; while (w) { int j = __ffs(w) - 1; w &= w - 1; acc += yb[(jb + 32 + j) * TT + t]; }
            w = bw.z; while (w) { int j = __ffs(w) - 1; w &= w - 1; acc += yb[(jb + 64 + j) * TT + t]; }
            w = bw.w; while (w) { int j = __ffs(w) - 1; w &= w - 1; acc += yb[(jb + 96 + j) * TT + t]; }
        }
        if (t < 31) total += fmaxf(ynext - acc, 0.0f);
    }
    #pragma unroll
    for (int off = 32; off; off >>= 1) total += __shfl_down(total, off, 64);
    if ((tid & 63) == 0) atomicAdd(out, total);
}

extern "C" void kernel_launch(void* const* d_in, const int* in_sizes, int n_in,
                              void* d_out, int out_size, void* d_ws, size_t ws_size,
                              hipStream_t stream) {
    const float* y = (const float*)d_in[0];     // (BS*M, TT) f32
    const int* coo = (const int*)d_in[1];       // (BS, 2, EE) delivered as int32
    float* out = (float*)d_out;

    hipMemsetAsync(out, 0, sizeof(float), stream);

    if (ws_size >= WS_NEED) {
        int* cnt = (int*)d_ws;
        unsigned int* bits = (unsigned int*)((char*)d_ws + CNT_BYTES);
        unsigned short* lists = (unsigned short*)((char*)d_ws + CNT_BYTES + BITS_BYTES);
        hipMemsetAsync(d_ws, 0, CNT_BYTES + BITS_BYTES, stream);   // counts + bitmap
        build_lists<<<(BS * EE / 4) / 256, 256, 0, stream>>>(coo, cnt, bits, lists);
        compute_lists<<<NROWS / 8, 256, 0, stream>>>(y, cnt, lists, out);
    } else if (ws_size >= BITS_BYTES) {
        unsigned int* bits = (unsigned int*)d_ws;
        hipMemsetAsync(bits, 0, BITS_BYTES, stream);
        build_adj<<<(BS * EE / 4) / 256, 256, 0, stream>>>(coo, bits);
        compute_reg<<<NROWS / 8, 256, 0, stream>>>(y, bits, out);
    } else {
        nil_reg_lds<<<BS * NCHUNK, 256, 0, stream>>>(y, coo, out);
    }
}

// Round 6
// 145.041 us; speedup vs baseline: 1.2324x; 1.2324x over previous
//
#include <hip/hip_runtime.h>

// Problem constants (fixed by setup_inputs): bs=8, m=4096, T=32, E=65536
#define M      4096
#define TT     32
#define BS     8
#define EE     65536
#define NROWS  (BS * M)                   // 32768
#define LIST_CAP 64                       // >> max row degree (Poisson mean 16)

// ws layout: [counts 128 KB][lists 4 MB]
#define CNT_BYTES  ((size_t)NROWS * 4)
#define LIST_BYTES ((size_t)NROWS * LIST_CAP * 2)
#define WS_NEED    (CNT_BYTES + LIST_BYTES)

// ---------------- Fast path: raw lists (dups kept), dedup at compute ----------------

// One returning atomicAdd + one 2B store per edge. No bitmap, no 16 MB memset.
__global__ __launch_bounds__(256) void build_lists(const int* __restrict__ coo,
                                                   int* __restrict__ cnt,
                                                   unsigned short* __restrict__ lists) {
    int idx = blockIdx.x * 256 + threadIdx.x;     // [0, BS*EE/4)
    int b = idx >> 14;                            // 16384 int4-groups per batch
    int e4 = idx & 16383;
    const int* base = coo + (size_t)b * 2 * EE;
    int4 s = ((const int4*)base)[e4];
    int4 g = ((const int4*)(base + EE))[e4];
    int rowbase = b * M;
    {
        int row = rowbase + (s.x & (M - 1));
        int p = atomicAdd(&cnt[row], 1);
        if (p < LIST_CAP) lists[(size_t)row * LIST_CAP + p] = (unsigned short)(g.x & (M - 1));
    }
    {
        int row = rowbase + (s.y & (M - 1));
        int p = atomicAdd(&cnt[row], 1);
        if (p < LIST_CAP) lists[(size_t)row * LIST_CAP + p] = (unsigned short)(g.y & (M - 1));
    }
    {
        int row = rowbase + (s.z & (M - 1));
        int p = atomicAdd(&cnt[row], 1);
        if (p < LIST_CAP) lists[(size_t)row * LIST_CAP + p] = (unsigned short)(g.z & (M - 1));
    }
    {
        int row = rowbase + (s.w & (M - 1));
        int p = atomicAdd(&cnt[row], 1);
        if (p < LIST_CAP) lists[(size_t)row * LIST_CAP + p] = (unsigned short)(g.w & (M - 1));
    }
}

// One 32-lane group per row (lane = t). In-LDS O(c^2) dedup, then masked gather.
__global__ __launch_bounds__(256) void compute_lists(const float* __restrict__ y,
                                                     const int* __restrict__ cnt,
                                                     const unsigned short* __restrict__ lists,
                                                     float* __restrict__ out) {
    __shared__ unsigned short slist[8][LIST_CAP];  // 1 KB
    __shared__ float wsum[4];
    const int tid = threadIdx.x;
    const int t = tid & 31;                        // lane within group = column t
    const int grp = tid >> 5;                      // 8 groups/block
    const int row = blockIdx.x * 8 + grp;          // [0, NROWS)
    const int b = row >> 12;
    const int i = row & (M - 1);

    const float* yb = y + (size_t)b * M * TT;
    int c = cnt[row]; if (c > LIST_CAP) c = LIST_CAP;
    const unsigned short* lp = lists + (size_t)row * LIST_CAP;

    // Phase A: copy this row's list into LDS (entries t and t+32).
    if (t < c) slist[grp][t] = lp[t];
    if (t + 32 < c) slist[grp][t + 32] = lp[t + 32];
    __syncthreads();

    // Phase B: dup flags (pure reads) — entry k is dup iff some k'<k equals it.
    bool dup0 = false, dup1 = false;
    if (t < c) {
        unsigned short v = slist[grp][t];
        for (int k = 0; k < t; ++k) dup0 |= (slist[grp][k] == v);
    }
    if (t + 32 < c) {
        unsigned short v = slist[grp][t + 32];
        for (int k = 0; k < t + 32; ++k) dup1 |= (slist[grp][k] == v);
    }
    __syncthreads();

    // Phase C: write sentinels for dups.
    if (dup0) slist[grp][t] = 0xFFFFu;
    if (dup1) slist[grp][t + 32] = 0xFFFFu;
    __syncthreads();

    // Phase D: masked gather. acc starts with the identity (eye) term.
    float acc = yb[i * TT + t];
    float ynext = (t < 31) ? yb[i * TT + t + 1] : 0.0f;

    for (int k0 = 0; k0 < c; k0 += 8) {
        uint4 lv = *(const uint4*)&slist[grp][k0];   // 8 entries, LDS broadcast
        int j[8] = { (int)(lv.x & 0xFFFF), (int)(lv.x >> 16),
                     (int)(lv.y & 0xFFFF), (int)(lv.y >> 16),
                     (int)(lv.z & 0xFFFF), (int)(lv.z >> 16),
                     (int)(lv.w & 0xFFFF), (int)(lv.w >> 16) };
        #pragma unroll
        for (int u = 0; u < 8; ++u) {
            float v = yb[(j[u] & (M - 1)) * TT + t];         // address always in-bounds
            bool valid = (k0 + u < c) && (j[u] != 0xFFFF);
            acc += valid ? v : 0.0f;                          // loads stay independent
        }
    }

    float v = (t < 31) ? fmaxf(ynext - acc, 0.0f) : 0.0f;
    #pragma unroll
    for (int off = 32; off; off >>= 1) v += __shfl_down(v, off, 64);

    if ((tid & 63) == 0) wsum[tid >> 6] = v;
    __syncthreads();
    if (tid == 0) atomicAdd(out, wsum[0] + wsum[1] + wsum[2] + wsum[3]);
}

// ---------------- Fallback (R3): LDS bitmap, no scratch ----------------
#define WPR    128
#define ROWS   64
#define NCHUNK (M / ROWS)

__global__ __launch_bounds__(256) void nil_reg_lds(const float* __restrict__ y,
                                                   const int* __restrict__ coo,
                                                   float* __restrict__ out) {
    __shared__ unsigned int bm[ROWS * WPR];
    const int tid = threadIdx.x;
    const int b = blockIdx.x / NCHUNK;
    const int chunk = blockIdx.x % NCHUNK;
    const int row0 = chunk * ROWS;
    for (int i = tid; i < ROWS * WPR; i += 256) bm[i] = 0;
    __syncthreads();
    const int* base = coo + (size_t)b * 2 * EE;
    for (int e = tid; e < EE; e += 256) {
        int src = base[e] & (M - 1);
        int tgt = base[EE + e] & (M - 1);
        int r = src - row0;
        if ((unsigned)r < (unsigned)ROWS)
            atomicOr(&bm[r * WPR + (tgt >> 5)], 1u << (tgt & 31));
    }
    __syncthreads();
    const float* yb = y + (size_t)b * M * TT;
    const int t = tid & 31;
    const int grp = tid >> 5;
    float total = 0.0f;
    for (int r = grp; r < ROWS; r += 8) {
        int i = row0 + r;
        float acc = yb[i * TT + t];
        float ynext = (t < 31) ? yb[i * TT + t + 1] : 0.0f;
        const uint4* rwp = (const uint4*)&bm[r * WPR];
        for (int w4 = 0; w4 < WPR / 4; ++w4) {
            uint4 bw = rwp[w4];
            int jb = w4 * 128;
            unsigned int w;
            w = bw.x; while (w) { int j = __ffs(w) - 1; w &= w - 1; acc += yb[(jb +      j) * TT + t]; }
            w = bw.y; while (w) { int j = __ffs(w) - 1; w &= w - 1; acc += yb[(jb + 32 + j) * TT + t]; }
            w = bw.z; while (w) { int j = __ffs(w) - 1; w &= w - 1; acc += yb[(jb + 64 + j) * TT + t]; }
            w = bw.w; while (w) { int j = __ffs(w) - 1; w &= w - 1; acc += yb[(jb + 96 + j) * TT + t]; }
        }
        if (t < 31) total += fmaxf(ynext - acc, 0.0f);
    }
    #pragma unroll
    for (int off = 32; off; off >>= 1) total += __shfl_down(total, off, 64);
    if ((tid & 63) == 0) atomicAdd(out, total);
}

extern "C" void kernel_launch(void* const* d_in, const int* in_sizes, int n_in,
                              void* d_out, int out_size, void* d_ws, size_t ws_size,
                              hipStream_t stream) {
    const float* y = (const float*)d_in[0];     // (BS*M, TT) f32
    const int* coo = (const int*)d_in[1];       // (BS, 2, EE) delivered as int32
    float* out = (float*)d_out;

    hipMemsetAsync(out, 0, sizeof(float), stream);

    if (ws_size >= WS_NEED) {
        int* cnt = (int*)d_ws;
        unsigned short* lists = (unsigned short*)((char*)d_ws + CNT_BYTES);
        hipMemsetAsync(cnt, 0, CNT_BYTES, stream);   // 128 KB only
        build_lists<<<(BS * EE / 4) / 256, 256, 0, stream>>>(coo, cnt, lists);
        compute_lists<<<NROWS / 8, 256, 0, stream>>>(y, cnt, lists, out);
    } else {
        nil_reg_lds<<<BS * NCHUNK, 256, 0, stream>>>(y, coo, out);
    }
}

// Round 7
// 115.904 us; speedup vs baseline: 1.5422x; 1.2514x over previous
//
#include <hip/hip_runtime.h>

// Problem constants (fixed by setup_inputs): bs=8, m=4096, T=32, E=65536
#define M      4096
#define TT     32
#define BS     8
#define EE     65536
#define NROWS  (BS * M)                   // 32768
#define LIST_CAP 64                       // >> max row degree (Poisson mean 16)
#define NBLK   (NROWS / 8)                // compute grid = 4096 blocks

// ws layout: [counts 128 KB][lists 4 MB][partials 16 KB]
#define CNT_BYTES  ((size_t)NROWS * 4)
#define LIST_BYTES ((size_t)NROWS * LIST_CAP * 2)
#define PART_BYTES ((size_t)NBLK * 4)
#define WS_NEED    (CNT_BYTES + LIST_BYTES + PART_BYTES)

// ---------------- Fast path ----------------

// One edge per thread: max TLP for the returning atomics (2048 blocks).
__global__ __launch_bounds__(256) void build_lists(const int* __restrict__ coo,
                                                   int* __restrict__ cnt,
                                                   unsigned short* __restrict__ lists) {
    int idx = blockIdx.x * 256 + threadIdx.x;     // [0, BS*EE)
    int b = idx >> 16;
    int e = idx & (EE - 1);
    const int* base = coo + (size_t)b * 2 * EE;
    int src = base[e] & (M - 1);
    int tgt = base[EE + e] & (M - 1);
    int row = b * M + src;
    int p = atomicAdd(&cnt[row], 1);
    if (p < LIST_CAP) lists[(size_t)row * LIST_CAP + p] = (unsigned short)tgt;
}

// One 32-lane group per row (lane = t). In-LDS O(c^2) dedup, masked gather,
// per-block partial sum via PLAIN STORE (no contended atomic).
__global__ __launch_bounds__(256) void compute_lists(const float* __restrict__ y,
                                                     const int* __restrict__ cnt,
                                                     const unsigned short* __restrict__ lists,
                                                     float* __restrict__ partials) {
    __shared__ unsigned short slist[8][LIST_CAP];  // 1 KB
    __shared__ float wsum[4];
    const int tid = threadIdx.x;
    const int t = tid & 31;                        // lane within group = column t
    const int grp = tid >> 5;                      // 8 groups/block
    const int row = blockIdx.x * 8 + grp;          // [0, NROWS)
    const int b = row >> 12;
    const int i = row & (M - 1);

    const float* yb = y + (size_t)b * M * TT;
    int c = cnt[row]; if (c > LIST_CAP) c = LIST_CAP;
    const unsigned short* lp = lists + (size_t)row * LIST_CAP;

    // Phase A: copy this row's list into LDS.
    if (t < c) slist[grp][t] = lp[t];
    if (t + 32 < c) slist[grp][t + 32] = lp[t + 32];
    __syncthreads();

    // Phase B: dup flags (pure reads) — entry k is dup iff some k'<k equals it.
    bool dup0 = false, dup1 = false;
    if (t < c) {
        unsigned short v = slist[grp][t];
        for (int k = 0; k < t; ++k) dup0 |= (slist[grp][k] == v);
    }
    if (t + 32 < c) {
        unsigned short v = slist[grp][t + 32];
        for (int k = 0; k < t + 32; ++k) dup1 |= (slist[grp][k] == v);
    }
    __syncthreads();

    // Phase C: sentinel the dups.
    if (dup0) slist[grp][t] = 0xFFFFu;
    if (dup1) slist[grp][t + 32] = 0xFFFFu;
    __syncthreads();

    // Phase D: masked gather. acc starts with the identity (eye) term.
    float acc = yb[i * TT + t];
    float ynext = (t < 31) ? yb[i * TT + t + 1] : 0.0f;

    for (int k0 = 0; k0 < c; k0 += 8) {
        uint4 lv = *(const uint4*)&slist[grp][k0];   // 8 entries, LDS broadcast
        int j[8] = { (int)(lv.x & 0xFFFF), (int)(lv.x >> 16),
                     (int)(lv.y & 0xFFFF), (int)(lv.y >> 16),
                     (int)(lv.z & 0xFFFF), (int)(lv.z >> 16),
                     (int)(lv.w & 0xFFFF), (int)(lv.w >> 16) };
        #pragma unroll
        for (int u = 0; u < 8; ++u) {
            float v = yb[(j[u] & (M - 1)) * TT + t];     // address always in-bounds
            bool valid = (k0 + u < c) && (j[u] != 0xFFFF);
            acc += valid ? v : 0.0f;                      // loads stay independent
        }
    }

    float v = (t < 31) ? fmaxf(ynext - acc, 0.0f) : 0.0f;
    #pragma unroll
    for (int off = 32; off; off >>= 1) v += __shfl_down(v, off, 64);

    if ((tid & 63) == 0) wsum[tid >> 6] = v;
    __syncthreads();
    if (tid == 0) partials[blockIdx.x] = wsum[0] + wsum[1] + wsum[2] + wsum[3];
}

// Single block sums the 4096 partials. No atomics anywhere.
__global__ __launch_bounds__(1024) void reduce_partials(const float* __restrict__ p,
                                                        float* __restrict__ out) {
    const int tid = threadIdx.x;
    float s = 0.0f;
    for (int k = tid; k < NBLK; k += 1024) s += p[k];
    #pragma unroll
    for (int off = 32; off; off >>= 1) s += __shfl_down(s, off, 64);
    __shared__ float ws[16];
    if ((tid & 63) == 0) ws[tid >> 6] = s;
    __syncthreads();
    if (tid == 0) {
        float tot = 0.0f;
        #pragma unroll
        for (int k = 0; k < 16; ++k) tot += ws[k];
        out[0] = tot;
    }
}

// ---------------- Fallback (R3): LDS bitmap, no scratch ----------------
#define WPR    128
#define ROWS   64
#define NCHUNK (M / ROWS)

__global__ __launch_bounds__(256) void nil_reg_lds(const float* __restrict__ y,
                                                   const int* __restrict__ coo,
                                                   float* __restrict__ out) {
    __shared__ unsigned int bm[ROWS * WPR];
    const int tid = threadIdx.x;
    const int b = blockIdx.x / NCHUNK;
    const int chunk = blockIdx.x % NCHUNK;
    const int row0 = chunk * ROWS;
    for (int i = tid; i < ROWS * WPR; i += 256) bm[i] = 0;
    __syncthreads();
    const int* base = coo + (size_t)b * 2 * EE;
    for (int e = tid; e < EE; e += 256) {
        int src = base[e] & (M - 1);
        int tgt = base[EE + e] & (M - 1);
        int r = src - row0;
        if ((unsigned)r < (unsigned)ROWS)
            atomicOr(&bm[r * WPR + (tgt >> 5)], 1u << (tgt & 31));
    }
    __syncthreads();
    const float* yb = y + (size_t)b * M * TT;
    const int t = tid & 31;
    const int grp = tid >> 5;
    float total = 0.0f;
    for (int r = grp; r < ROWS; r += 8) {
        int i = row0 + r;
        float acc = yb[i * TT + t];
        float ynext = (t < 31) ? yb[i * TT + t + 1] : 0.0f;
        const uint4* rwp = (const uint4*)&bm[r * WPR];
        for (int w4 = 0; w4 < WPR / 4; ++w4) {
            uint4 bw = rwp[w4];
            int jb = w4 * 128;
            unsigned int w;
            w = bw.x; while (w) { int j = __ffs(w) - 1; w &= w - 1; acc += yb[(jb +      j) * TT + t]; }
            w = bw.y; while (w) { int j = __ffs(w) - 1; w &= w - 1; acc += yb[(jb + 32 + j) * TT + t]; }
            w = bw.z; while (w) { int j = __ffs(w) - 1; w &= w - 1; acc += yb[(jb + 64 + j) * TT + t]; }
            w = bw.w; while (w) { int j = __ffs(w) - 1; w &= w - 1; acc += yb[(jb + 96 + j) * TT + t]; }
        }
        if (t < 31) total += fmaxf(ynext - acc, 0.0f);
    }
    #pragma unroll
    for (int off = 32; off; off >>= 1) total += __shfl_down(total, off, 64);
    if ((tid & 63) == 0) atomicAdd(out, total);
}

extern "C" void kernel_launch(void* const* d_in, const int* in_sizes, int n_in,
                              void* d_out, int out_size, void* d_ws, size_t ws_size,
                              hipStream_t stream) {
    const float* y = (const float*)d_in[0];     // (BS*M, TT) f32
    const int* coo = (const int*)d_in[1];       // (BS, 2, EE) delivered as int32
    float* out = (float*)d_out;

    if (ws_size >= WS_NEED) {
        int* cnt = (int*)d_ws;
        unsigned short* lists = (unsigned short*)((char*)d_ws + CNT_BYTES);
        float* partials = (float*)((char*)d_ws + CNT_BYTES + LIST_BYTES);
        hipMemsetAsync(cnt, 0, CNT_BYTES, stream);   // 128 KB only
        build_lists<<<(BS * EE) / 256, 256, 0, stream>>>(coo, cnt, lists);
        compute_lists<<<NBLK, 256, 0, stream>>>(y, cnt, lists, partials);
        reduce_partials<<<1, 1024, 0, stream>>>(partials, out);
    } else {
        hipMemsetAsync(out, 0, sizeof(float), stream);
        nil_reg_lds<<<BS * NCHUNK, 256, 0, stream>>>(y, coo, out);
    }
}